// Round 10
// baseline (3973.519 us; speedup 1.0000x reference)
//
#include <hip/hip_runtime.h>

// R15: stream n-gate Wh frags from an L2-resident ws slice instead of LDS.
// Model correction: VGPR_Count reports 2-reg units -> R7 is at the FULL
// 256-reg/wave ceiling; R13's all-resident plan necessarily spilled (likely
// cause of its pathology). Weight frags must stream from somewhere; LDS was
// the bottleneck pipe (12cyc/b128 issue, 208 instr/CU-step ~2500cyc). Fix:
// whn (16 frags/wave-step, step-invariant) is pre-converted once into a
// PRIVATE 128KB per-block ws slice (32x128KB = 4MB, L2-resident per XCD;
// L2 hits don't count in FETCH) and read per step as global_load_dwordx4 on
// the idle VMEM pipe. LDS drops to h+x only (80 instr/CU-step, 20KB), the
// compiler's vmcnt scheduling hides L2 latency under the MFMA stream.
// Same-block store->load visibility: __syncthreads implies vmcnt(0) drain.
// Everything else is R7 verbatim (proven 1845us, absmax 0.00195).

typedef short v8s __attribute__((ext_vector_type(8)));   // 8 bf16
typedef float f32x4 __attribute__((ext_vector_type(4)));

#define LOG2E 1.4426950408889634f
#define WS15_NEED (32ull * 131072ull)      // 4 MB

__device__ __forceinline__ unsigned short f2b(float f) {
    unsigned int u = __float_as_uint(f);
    u += 0x7FFFu + ((u >> 16) & 1u);       // RNE
    return (unsigned short)(u >> 16);
}
__device__ __forceinline__ float b2f(unsigned short h) {
    return __uint_as_float(((unsigned int)h) << 16);
}
__device__ __forceinline__ v8s cvt8(f32x4 a, f32x4 b) {
    v8s r;
#pragma unroll
    for (int j = 0; j < 4; ++j) { r[j] = (short)f2b(a[j]); r[4 + j] = (short)f2b(b[j]); }
    return r;
}
__device__ __forceinline__ v8s wfrag(const float* src, float s) {
    f32x4 a = *(const f32x4*)src, b = *(const f32x4*)(src + 4);
    a *= s; b *= s;
    return cvt8(a, b);
}
__device__ __forceinline__ float rcpf(float v) {
#if __has_builtin(__builtin_amdgcn_rcpf)
    return __builtin_amdgcn_rcpf(v);
#else
    return 1.0f / v;
#endif
}
__device__ __forceinline__ float exp2f_(float v) {
#if __has_builtin(__builtin_amdgcn_exp2f)
    return __builtin_amdgcn_exp2f(v);
#else
    return __exp2f(v);
#endif
}
// sigmoid of log2e-prescaled preactivation (HW-validated R6/R7/R9/R12)
__device__ __forceinline__ float sg(float v) { return rcpf(1.0f + exp2f_(-v)); }
__device__ __forceinline__ f32x4 MF(v8s a, v8s b, f32x4 c) {
    return __builtin_amdgcn_mfma_f32_16x16x32_bf16(a, b, c, 0, 0, 0);
}
// A-frag order index for element (row, k): u16 units
__device__ __forceinline__ int fidx(int row, int k) {
    return ((k >> 5) << 9) + ((((k >> 3) & 3) << 4) + row) * 8 + (k & 7);
}

// ======================= R15: L2-streamed whn =======================
// LDS: h ping-pong 2*8192 | x ping-pong 2*2048 = 20480 B
#define L15_X    16384
#define L15_SIZE 20480

extern "C" __global__ void __launch_bounds__(512, 2)
gru_v15(const float* __restrict__ x, const float* __restrict__ Wx,
        const float* __restrict__ Wh, const float* __restrict__ bias,
        const float* __restrict__ fcw, const float* __restrict__ fcb,
        v8s* __restrict__ ws, float* __restrict__ out)
{
    extern __shared__ char lds[];
    char* hl = lds;                        // 16KB h ping-pong
    char* xl = lds + L15_X;                // 4KB x ping-pong

    const int tid = threadIdx.x;
    const int w = tid >> 6, l = tid & 63;
    const int cl = l & 15, kg = l >> 4;
    const int b0 = blockIdx.x << 4;
    const int tiles[6] = {2*w, 2*w+1, 16+2*w, 17+2*w, 32+2*w, 33+2*w};

    // private per-block whn slice in ws (128 frags * 64 lanes * 16B = 128KB)
    v8s* wsn = ws + (size_t)blockIdx.x * 8192;   // v8s units: 128*64

    // prologue: convert n-gate Wh (rows 512..767) -> frag-format, ws slice
    for (int f = w; f < 128; f += 8) {
        int t5 = f >> 3, ks = f & 7;
        const float* src = Wh + (size_t)(512 + t5*16 + cl)*256 + ks*32 + kg*8;
        wsn[f*64 + l] = wfrag(src, 2.0f*LOG2E);
    }

    // r,z Wh tiles register-resident, log2e-scaled (128 regs)
    v8s whB[4][8];
#pragma unroll
    for (int tt = 0; tt < 4; ++tt) {
        const float* src = Wh + (size_t)(tiles[tt]*16 + cl)*256 + kg*8;
#pragma unroll
        for (int ks = 0; ks < 8; ++ks)
            whB[tt][ks] = wfrag(src + ks*32, LOG2E);
    }
    // Wx frags resident: 6 tiles x 2 k-slices, prescaled (48 regs)
    v8s wxr[12];
#pragma unroll
    for (int tt = 0; tt < 6; ++tt) {
        const float sc = (tt < 4) ? LOG2E : 2.0f*LOG2E;
        const float* s0 = Wx + (size_t)(tiles[tt]*16 + cl)*64 + kg*8;
        wxr[tt*2]   = wfrag(s0, sc);
        wxr[tt*2+1] = wfrag(s0 + 32, sc);
    }
    // prescaled bias (folded into accumulator init each step)
    float brv[2], bzv[2], bhv[2];
#pragma unroll
    for (int p = 0; p < 2; ++p) {
        int ch = (w << 5) + (p << 4) + cl;
        brv[p] = bias[ch] * LOG2E;
        bzv[p] = bias[256 + ch] * LOG2E;
        bhv[p] = bias[512 + ch] * 2.0f*LOG2E;
    }

    // h0 = 0 (buffer 0)
    for (int i = tid; i < 2048; i += 512) ((unsigned int*)hl)[i] = 0u;
    float hprev[8] = {0, 0, 0, 0, 0, 0, 0, 0};

    // x staging: t=0 into buffer 0 (2 bf16/thread)
    const int xr = tid >> 5, xc = (tid & 31) << 1;
    const int xidx = fidx(xr, xc);
    const float* xp = x + (((size_t)(b0 + xr)) << 16) + xc;
    {
        unsigned int pk = (unsigned int)f2b(xp[0]) | ((unsigned int)f2b(xp[1]) << 16);
        *(unsigned int*)(xl + xidx*2) = pk;
    }
    xp += 64;
    const int wn0 = (2*w)*8, wn1 = (2*w+1)*8;
    const v8s* wnp0 = wsn + wn0*64 + l;    // this wave's n-gate tile 0 frags
    const v8s* wnp1 = wsn + wn1*64 + l;    // tile 1 (stride 64 v8s per ks)

    for (int t = 0; t < 1024; ++t) {
        __syncthreads();                   // implies vmcnt(0): prologue visible
        const int cur = t & 1;
        const v8s* hb = (const v8s*)(hl + cur*8192);
        const v8s* xb = (const v8s*)(xl + cur*2048);

        // prefetch next timestep's x slice (8B/lane, consumed at step end)
        float xv0 = 0.0f, xv1 = 0.0f;
        if (t < 1023) { xv0 = xp[0]; xv1 = xp[1]; xp += 64; }

        // acc init = prescaled bias (r,z,n-x); n-h starts at 0
        f32x4 acc[8];
        acc[0] = f32x4{brv[0], brv[0], brv[0], brv[0]};
        acc[1] = f32x4{brv[1], brv[1], brv[1], brv[1]};
        acc[2] = f32x4{bzv[0], bzv[0], bzv[0], bzv[0]};
        acc[3] = f32x4{bzv[1], bzv[1], bzv[1], bzv[1]};
        acc[4] = f32x4{0, 0, 0, 0};
        acc[5] = f32x4{0, 0, 0, 0};
        acc[6] = f32x4{bhv[0], bhv[0], bhv[0], bhv[0]};
        acc[7] = f32x4{bhv[1], bhv[1], bhv[1], bhv[1]};

#pragma unroll
        for (int ks = 0; ks < 8; ++ks) {
            v8s a  = hb[(ks << 6) + l];
            v8s n0 = wnp0[ks << 6];        // global_load_dwordx4, L2-hot
            v8s n1 = wnp1[ks << 6];
            acc[0] = MF(a, whB[0][ks], acc[0]);
            acc[1] = MF(a, whB[1][ks], acc[1]);
            acc[2] = MF(a, whB[2][ks], acc[2]);
            acc[3] = MF(a, whB[3][ks], acc[3]);
            acc[4] = MF(a, n0, acc[4]);
            acc[5] = MF(a, n1, acc[5]);
        }
#pragma unroll
        for (int k2 = 0; k2 < 2; ++k2) {
            v8s ax = xb[(k2 << 6) + l];
            acc[0] = MF(ax, wxr[0  + k2], acc[0]);
            acc[1] = MF(ax, wxr[2  + k2], acc[1]);
            acc[2] = MF(ax, wxr[4  + k2], acc[2]);
            acc[3] = MF(ax, wxr[6  + k2], acc[3]);
            acc[6] = MF(ax, wxr[8  + k2], acc[6]);
            acc[7] = MF(ax, wxr[10 + k2], acc[7]);
        }

        unsigned short* hn = (unsigned short*)(hl + (cur ^ 1) * 8192);
#pragma unroll
        for (int p = 0; p < 2; ++p) {
            const int ch = (w << 5) + (p << 4) + cl;
            const int chbase = ((ch >> 5) << 9) + (((ch >> 3) & 3) << 7) + (ch & 7);
#pragma unroll
            for (int i = 0; i < 4; ++i) {
                float rg = sg(acc[p][i]);
                float zg = sg(acc[2 + p][i]);
                float nv = __builtin_fmaf(rg, acc[4 + p][i], acc[6 + p][i]);
                float ng = __builtin_fmaf(2.0f, sg(nv), -1.0f);
                float hy = ng + zg * (hprev[p*4 + i] - ng);
                hprev[p*4 + i] = hy;
                hn[chbase + ((kg << 2) + i) * 8] = f2b(hy);
            }
        }
        // stage next x into the other buffer
        if (t < 1023) {
            unsigned int pk = (unsigned int)f2b(xv0) | ((unsigned int)f2b(xv1) << 16);
            *(unsigned int*)(xl + ((cur ^ 1) * 2048) + xidx*2) = pk;
        }
    }

    __syncthreads();
    // logits from hT (buffer 0 after 1024 steps)
    const unsigned short* hf = (const unsigned short*)hl;
    if (tid < 160) {
        int row = tid / 10, cls = tid - row * 10;
        float s = fcb[cls];
        const float* wrow = fcw + cls * 256;
        for (int k = 0; k < 256; ++k)
            s += b2f(hf[fidx(row, k)]) * wrow[k];
        out[(b0 + row)*10 + cls] = s;
    }
}

// ================= fallback (ws < 4MB): R7 kernel, proven 1845us =================
#define LDS7_H    131072
#define LDS7_X    147456
#define LDS7_SIZE 151552

extern "C" __global__ void __launch_bounds__(512, 2)
gru_v7(const float* __restrict__ x, const float* __restrict__ Wx,
       const float* __restrict__ Wh, const float* __restrict__ bias,
       const float* __restrict__ fcw, const float* __restrict__ fcb,
       float* __restrict__ out)
{
    extern __shared__ char lds[];
    v8s* whn = (v8s*)lds;
    char* hl = lds + LDS7_H;
    char* xl = lds + LDS7_X;

    const int tid = threadIdx.x;
    const int w = tid >> 6, l = tid & 63;
    const int cl = l & 15, kg = l >> 4;
    const int b0 = blockIdx.x << 4;
    const int tiles[6] = {2*w, 2*w+1, 16+2*w, 17+2*w, 32+2*w, 33+2*w};

    for (int f = w; f < 128; f += 8) {
        int t5 = f >> 3, ks = f & 7;
        const float* src = Wh + (size_t)(512 + t5*16 + cl)*256 + ks*32 + kg*8;
        whn[f*64 + l] = wfrag(src, 2.0f*LOG2E);
    }
    v8s whB[4][8];
#pragma unroll
    for (int tt = 0; tt < 4; ++tt) {
        const float* src = Wh + (size_t)(tiles[tt]*16 + cl)*256 + kg*8;
#pragma unroll
        for (int ks = 0; ks < 8; ++ks)
            whB[tt][ks] = wfrag(src + ks*32, LOG2E);
    }
    v8s wxr[12];
#pragma unroll
    for (int tt = 0; tt < 6; ++tt) {
        const float sc = (tt < 4) ? LOG2E : 2.0f*LOG2E;
        const float* s0 = Wx + (size_t)(tiles[tt]*16 + cl)*64 + kg*8;
        wxr[tt*2]   = wfrag(s0, sc);
        wxr[tt*2+1] = wfrag(s0 + 32, sc);
    }
    float brv[2], bzv[2], bhv[2];
#pragma unroll
    for (int p = 0; p < 2; ++p) {
        int ch = (w << 5) + (p << 4) + cl;
        brv[p] = bias[ch] * LOG2E;
        bzv[p] = bias[256 + ch] * LOG2E;
        bhv[p] = bias[512 + ch] * 2.0f*LOG2E;
    }
    for (int i = tid; i < 2048; i += 512) ((unsigned int*)hl)[i] = 0u;
    float hprev[8] = {0, 0, 0, 0, 0, 0, 0, 0};
    const int xr = tid >> 5, xc = (tid & 31) << 1;
    const int xidx = fidx(xr, xc);
    const float* xp = x + (((size_t)(b0 + xr)) << 16) + xc;
    {
        unsigned int pk = (unsigned int)f2b(xp[0]) | ((unsigned int)f2b(xp[1]) << 16);
        *(unsigned int*)(xl + xidx*2) = pk;
    }
    xp += 64;
    const int wn0 = (2*w)*8, wn1 = (2*w+1)*8;

    for (int t = 0; t < 1024; ++t) {
        __syncthreads();
        const int cur = t & 1;
        const v8s* hb = (const v8s*)(hl + cur*8192);
        const v8s* xb = (const v8s*)(xl + cur*2048);
        float xv0 = 0.0f, xv1 = 0.0f;
        if (t < 1023) { xv0 = xp[0]; xv1 = xp[1]; xp += 64; }

        f32x4 acc[8];
        acc[0] = f32x4{brv[0], brv[0], brv[0], brv[0]};
        acc[1] = f32x4{brv[1], brv[1], brv[1], brv[1]};
        acc[2] = f32x4{bzv[0], bzv[0], bzv[0], bzv[0]};
        acc[3] = f32x4{bzv[1], bzv[1], bzv[1], bzv[1]};
        acc[4] = f32x4{0, 0, 0, 0};
        acc[5] = f32x4{0, 0, 0, 0};
        acc[6] = f32x4{bhv[0], bhv[0], bhv[0], bhv[0]};
        acc[7] = f32x4{bhv[1], bhv[1], bhv[1], bhv[1]};
#pragma unroll
        for (int ks = 0; ks < 8; ++ks) {
            v8s a  = hb[(ks << 6) + l];
            v8s n0 = whn[(wn0 + ks)*64 + l];
            v8s n1 = whn[(wn1 + ks)*64 + l];
            acc[0] = MF(a, whB[0][ks], acc[0]);
            acc[1] = MF(a, whB[1][ks], acc[1]);
            acc[2] = MF(a, whB[2][ks], acc[2]);
            acc[3] = MF(a, whB[3][ks], acc[3]);
            acc[4] = MF(a, n0, acc[4]);
            acc[5] = MF(a, n1, acc[5]);
        }
#pragma unroll
        for (int k2 = 0; k2 < 2; ++k2) {
            v8s ax = xb[(k2 << 6) + l];
            acc[0] = MF(ax, wxr[0  + k2], acc[0]);
            acc[1] = MF(ax, wxr[2  + k2], acc[1]);
            acc[2] = MF(ax, wxr[4  + k2], acc[2]);
            acc[3] = MF(ax, wxr[6  + k2], acc[3]);
            acc[6] = MF(ax, wxr[8  + k2], acc[6]);
            acc[7] = MF(ax, wxr[10 + k2], acc[7]);
        }
        unsigned short* hn = (unsigned short*)(hl + (cur ^ 1) * 8192);
#pragma unroll
        for (int p = 0; p < 2; ++p) {
            const int ch = (w << 5) + (p << 4) + cl;
            const int chbase = ((ch >> 5) << 9) + (((ch >> 3) & 3) << 7) + (ch & 7);
#pragma unroll
            for (int i = 0; i < 4; ++i) {
                float rg = sg(acc[p][i]);
                float zg = sg(acc[2 + p][i]);
                float nv = __builtin_fmaf(rg, acc[4 + p][i], acc[6 + p][i]);
                float ng = __builtin_fmaf(2.0f, sg(nv), -1.0f);
                float hy = ng + zg * (hprev[p*4 + i] - ng);
                hprev[p*4 + i] = hy;
                hn[chbase + ((kg << 2) + i) * 8] = f2b(hy);
            }
        }
        if (t < 1023) {
            unsigned int pk = (unsigned int)f2b(xv0) | ((unsigned int)f2b(xv1) << 16);
            *(unsigned int*)(xl + ((cur ^ 1) * 2048) + xidx*2) = pk;
        }
    }

    __syncthreads();
    const unsigned short* hf = (const unsigned short*)hl;
    if (tid < 160) {
        int row = tid / 10, cls = tid - row * 10;
        float s = fcb[cls];
        const float* wrow = fcw + cls * 256;
        for (int k = 0; k < 256; ++k)
            s += b2f(hf[fidx(row, k)]) * wrow[k];
        out[(b0 + row)*10 + cls] = s;
    }
}

extern "C" void kernel_launch(void* const* d_in, const int* in_sizes, int n_in,
                              void* d_out, int out_size, void* d_ws, size_t ws_size,
                              hipStream_t stream) {
    const float* x    = (const float*)d_in[0];
    const float* Wx   = (const float*)d_in[1];
    const float* Wh   = (const float*)d_in[2];
    const float* bias = (const float*)d_in[3];
    const float* fcw  = (const float*)d_in[4];
    const float* fcb  = (const float*)d_in[5];

    if (ws_size >= WS15_NEED) {
        (void)hipFuncSetAttribute((const void*)gru_v15,
                                  hipFuncAttributeMaxDynamicSharedMemorySize, L15_SIZE);
        gru_v15<<<dim3(32), dim3(512), L15_SIZE, stream>>>(
            x, Wx, Wh, bias, fcw, fcb, (v8s*)d_ws, (float*)d_out);
    } else {
        (void)hipFuncSetAttribute((const void*)gru_v7,
                                  hipFuncAttributeMaxDynamicSharedMemorySize, LDS7_SIZE);
        gru_v7<<<dim3(32), dim3(512), LDS7_SIZE, stream>>>(
            x, Wx, Wh, bias, fcw, fcb, (float*)d_out);
    }
}